// Round 1
// baseline (728.101 us; speedup 1.0000x reference)
//
#include <hip/hip_runtime.h>
#include <hip/hip_bf16.h>
#include <stdint.h>

#define T_SEQ 2048
#define D_MODEL 2048
#define N_HEADS 16
#define HEAD_DIM 128

typedef __hip_bfloat16 bf16_t;
typedef __attribute__((ext_vector_type(8))) short short8;
typedef __attribute__((ext_vector_type(4))) short short4v;
typedef __attribute__((ext_vector_type(4))) float f32x4;

__device__ __forceinline__ unsigned short f2bf(float x) {
  union { float f; unsigned u; } c; c.f = x;
  unsigned u = c.u;
  u += 0x7fffu + ((u >> 16) & 1u);   // RNE
  return (unsigned short)(u >> 16);
}
__device__ __forceinline__ float bf2f(short v) {
  union { unsigned u; float f; } c;
  c.u = ((unsigned)(unsigned short)v) << 16;
  return c.f;
}
__device__ __forceinline__ void async16(const bf16_t* g, bf16_t* l) {
  __builtin_amdgcn_global_load_lds(
      (const __attribute__((address_space(1))) void*)g,
      (__attribute__((address_space(3))) void*)l, 16, 0, 0);
}

// ---------------- f32 -> bf16 conversion ----------------
__global__ __launch_bounds__(256) void cvt_kernel(const float* __restrict__ in,
                                                  unsigned short* __restrict__ out,
                                                  int n4) {
  int i = blockIdx.x * 256 + threadIdx.x;
  if (i >= n4) return;
  float4 v = ((const float4*)in)[i];
  short4v o;
  o[0] = (short)f2bf(v.x); o[1] = (short)f2bf(v.y);
  o[2] = (short)f2bf(v.z); o[3] = (short)f2bf(v.w);
  ((short4v*)out)[i] = o;
}

// ---------------- GEMM C[M,N] = A[M,K] * B[N,K]^T  (bf16 in, f32 acc) ----------------
// 128x128 tile, BK=32, 256 threads (4 waves 2x2), m97-style 2-barrier loop.
template<int F32OUT>
__global__ __launch_bounds__(256) void gemm_bt_kernel(
    const bf16_t* __restrict__ A, const bf16_t* __restrict__ Bm,
    float* __restrict__ Cf, unsigned short* __restrict__ Cb,
    int M, int N, int K) {
  __shared__ bf16_t As[128 * 32];
  __shared__ bf16_t Bs[128 * 32];
  const int tid = threadIdx.x;
  const int lane = tid & 63;
  const int wv = tid >> 6;
  const int wr = wv >> 1, wc = wv & 1;
  const int l15 = lane & 15, g = lane >> 4;
  const int m0 = blockIdx.y * 128, n0 = blockIdx.x * 128;

  const int srow = tid >> 2;          // 0..63
  const int scol = (tid & 3) << 3;    // 0,8,16,24

  f32x4 acc[4][4];
#pragma unroll
  for (int i = 0; i < 4; ++i)
#pragma unroll
    for (int j = 0; j < 4; ++j)
#pragma unroll
      for (int e = 0; e < 4; ++e) acc[i][j][e] = 0.0f;

  for (int k0 = 0; k0 < K; k0 += 32) {
    __syncthreads();
    const bf16_t* ag = A + (size_t)(m0 + srow) * K + k0 + scol;
    const bf16_t* bg = Bm + (size_t)(n0 + srow) * K + k0 + scol;
    bf16_t* al = As + wv * 512;   // wave-uniform LDS base; HW adds lane*16B
    bf16_t* bl = Bs + wv * 512;
    async16(ag, al);
    async16(ag + (size_t)64 * K, al + 2048);
    async16(bg, bl);
    async16(bg + (size_t)64 * K, bl + 2048);
    __syncthreads();   // compiler emits vmcnt(0) before barrier -> loads landed

    short8 af[4], bfr[4];
#pragma unroll
    for (int mi = 0; mi < 4; ++mi)
      af[mi] = *(const short8*)(As + (wr * 64 + mi * 16 + l15) * 32 + g * 8);
#pragma unroll
    for (int ni = 0; ni < 4; ++ni)
      bfr[ni] = *(const short8*)(Bs + (wc * 64 + ni * 16 + l15) * 32 + g * 8);
#pragma unroll
    for (int mi = 0; mi < 4; ++mi)
#pragma unroll
      for (int ni = 0; ni < 4; ++ni)
        acc[mi][ni] = __builtin_amdgcn_mfma_f32_16x16x32_bf16(af[mi], bfr[ni], acc[mi][ni], 0, 0, 0);
  }

#pragma unroll
  for (int mi = 0; mi < 4; ++mi)
#pragma unroll
    for (int ni = 0; ni < 4; ++ni)
#pragma unroll
      for (int r = 0; r < 4; ++r) {
        int mr = m0 + wr * 64 + mi * 16 + g * 4 + r;
        int nc = n0 + wc * 64 + ni * 16 + l15;
        if (F32OUT)
          Cf[(size_t)mr * N + nc] = acc[mi][ni][r];
        else
          Cb[(size_t)mr * N + nc] = f2bf(acc[mi][ni][r]);
      }
}

// ---------------- RoPE + split + V transpose ----------------
// qkv [B,T,3D] bf16 -> q,k [BH,T,HD] bf16 (q pre-scaled by 1/sqrt(HD)), vT [BH,HD,T] bf16
__global__ __launch_bounds__(256) void rope_kernel(
    const bf16_t* __restrict__ qkv,
    const float* __restrict__ cosb, const float* __restrict__ sinb,
    bf16_t* __restrict__ qo, bf16_t* __restrict__ ko, bf16_t* __restrict__ vT) {
  const int nTT = T_SEQ / 64;
  const int bx = blockIdx.x;
  const int bh = bx / nTT, tt = bx % nTT;
  const int b = bh / N_HEADS, h = bh % N_HEADS;
  const int tid = threadIdx.x;
  __shared__ bf16_t vlds[64][136];   // +8 pad breaks bank alignment on transpose read

  const float SC = 0.08838834764831845f;  // 1/sqrt(128)

#pragma unroll
  for (int it = 0; it < 2; ++it) {
    int item = it * 256 + tid;      // 0..511
    int r = item >> 3, cg = item & 7;
    int t = tt * 64 + r;
    int c0 = cg * 8;                // hd offset in first half [0,64)
    size_t base = ((size_t)b * T_SEQ + t) * (size_t)(3 * D_MODEL) + (size_t)h * HEAD_DIM;

    float cs0[8], sn0[8], cs1[8], sn1[8];
    {
      const float* cp = cosb + (size_t)t * HEAD_DIM + c0;
      const float* sp = sinb + (size_t)t * HEAD_DIM + c0;
      float4 a0 = *(const float4*)(cp), a1 = *(const float4*)(cp + 4);
      float4 b0 = *(const float4*)(cp + 64), b1 = *(const float4*)(cp + 68);
      float4 s0 = *(const float4*)(sp), s1 = *(const float4*)(sp + 4);
      float4 t0 = *(const float4*)(sp + 64), t1 = *(const float4*)(sp + 68);
      cs0[0]=a0.x; cs0[1]=a0.y; cs0[2]=a0.z; cs0[3]=a0.w; cs0[4]=a1.x; cs0[5]=a1.y; cs0[6]=a1.z; cs0[7]=a1.w;
      cs1[0]=b0.x; cs1[1]=b0.y; cs1[2]=b0.z; cs1[3]=b0.w; cs1[4]=b1.x; cs1[5]=b1.y; cs1[6]=b1.z; cs1[7]=b1.w;
      sn0[0]=s0.x; sn0[1]=s0.y; sn0[2]=s0.z; sn0[3]=s0.w; sn0[4]=s1.x; sn0[5]=s1.y; sn0[6]=s1.z; sn0[7]=s1.w;
      sn1[0]=t0.x; sn1[1]=t0.y; sn1[2]=t0.z; sn1[3]=t0.w; sn1[4]=t1.x; sn1[5]=t1.y; sn1[6]=t1.z; sn1[7]=t1.w;
    }

    // Q (scaled) and K (unscaled)
#pragma unroll
    for (int sec = 0; sec < 2; ++sec) {
      size_t sbase = base + (size_t)sec * D_MODEL;
      short8 lo = *(const short8*)(qkv + sbase + c0);
      short8 hi = *(const short8*)(qkv + sbase + 64 + c0);
      short8 olo, ohi;
#pragma unroll
      for (int e = 0; e < 8; ++e) {
        float xl = bf2f(lo[e]), xh = bf2f(hi[e]);
        float rl = xl * cs0[e] - xh * sn0[e];
        float rh = xh * cs1[e] + xl * sn1[e];
        if (sec == 0) { rl *= SC; rh *= SC; }
        olo[e] = (short)f2bf(rl);
        ohi[e] = (short)f2bf(rh);
      }
      bf16_t* dst = (sec == 0 ? qo : ko) + ((size_t)bh * T_SEQ + t) * HEAD_DIM + c0;
      *(short8*)dst = olo;
      *(short8*)(dst + 64) = ohi;
    }

    // V into LDS (row-major tile)
    short8 v0 = *(const short8*)(qkv + base + 2 * D_MODEL + c0);
    short8 v1 = *(const short8*)(qkv + base + 2 * D_MODEL + 64 + c0);
    *(short8*)&vlds[r][c0] = v0;
    *(short8*)&vlds[r][64 + c0] = v1;
  }
  __syncthreads();

  // transposed write: vT[bh][hd][t], 64B contiguous per thread
  int hd = tid >> 1, hf = tid & 1;
  bf16_t* dst = vT + ((size_t)bh * HEAD_DIM + hd) * T_SEQ + tt * 64 + hf * 32;
#pragma unroll
  for (int jj = 0; jj < 4; ++jj) {
    short8 o;
#pragma unroll
    for (int e = 0; e < 8; ++e)
      o[e] = *(const short*)&vlds[hf * 32 + jj * 8 + e][hd];
    *(short8*)(dst + jj * 8) = o;
  }
}

// ---------------- causal flash attention ----------------
// q,k [BH,T,HD] (q pre-scaled), vT [BH,HD,T] -> attn [B,T,D] bf16
__global__ __launch_bounds__(256) void attn_kernel(
    const bf16_t* __restrict__ q, const bf16_t* __restrict__ k,
    const bf16_t* __restrict__ vT, unsigned short* __restrict__ attn) {
  const int nQT = T_SEQ / 64;   // 32
  const int bx = blockIdx.x;
  const int bh = bx / nQT;
  const int qt = (nQT - 1) - (bx % nQT);   // long blocks first
  const int b = bh / N_HEADS, h = bh % N_HEADS;
  const int tid = threadIdx.x;
  const int w = tid >> 6, lane = tid & 63;
  const int l15 = lane & 15, g = lane >> 4;
  const float LOG2E = 1.44269504088896340736f;

  __shared__ bf16_t plds[4][16][72];   // per-wave P buffer, padded stride

  const bf16_t* qb = q + (size_t)bh * T_SEQ * HEAD_DIM;
  const bf16_t* kb = k + (size_t)bh * T_SEQ * HEAD_DIM;
  const bf16_t* vb = vT + (size_t)bh * HEAD_DIM * T_SEQ;

  const int qrow = qt * 64 + w * 16 + l15;
  short8 qf[4];
#pragma unroll
  for (int kk = 0; kk < 4; ++kk)
    qf[kk] = *(const short8*)(qb + (size_t)qrow * HEAD_DIM + kk * 32 + g * 8);

  float m[4], l[4];
  f32x4 acc[8];
#pragma unroll
  for (int r = 0; r < 4; ++r) { m[r] = -3.0e38f; l[r] = 0.0f; }
#pragma unroll
  for (int fh = 0; fh < 8; ++fh)
#pragma unroll
    for (int e = 0; e < 4; ++e) acc[fh][e] = 0.0f;

  for (int kt = 0; kt <= qt; ++kt) {
    // S = Q K^T  (S[q,kv]; q pre-scaled)
    f32x4 s[4];
#pragma unroll
    for (int f = 0; f < 4; ++f)
#pragma unroll
      for (int e = 0; e < 4; ++e) s[f][e] = 0.0f;
#pragma unroll
    for (int f = 0; f < 4; ++f) {
      const bf16_t* kr = kb + (size_t)(kt * 64 + f * 16 + l15) * HEAD_DIM + g * 8;
#pragma unroll
      for (int kk = 0; kk < 4; ++kk) {
        short8 kf = *(const short8*)(kr + kk * 32);
        s[f] = __builtin_amdgcn_mfma_f32_16x16x32_bf16(qf[kk], kf, s[f], 0, 0, 0);
      }
    }
    if (kt == qt) {   // diagonal tile causal mask
#pragma unroll
      for (int f = 0; f < 4; ++f) {
        int kv = f * 16 + l15;
#pragma unroll
        for (int r = 0; r < 4; ++r) {
          int qq = w * 16 + g * 4 + r;
          if (kv > qq) s[f][r] = -3.0e38f;
        }
      }
    }
    // online softmax (rows live in 16-lane groups -> shfl_xor over bits 0..3)
    float rmax[4];
#pragma unroll
    for (int r = 0; r < 4; ++r)
      rmax[r] = fmaxf(fmaxf(s[0][r], s[1][r]), fmaxf(s[2][r], s[3][r]));
#pragma unroll
    for (int off = 1; off < 16; off <<= 1)
#pragma unroll
      for (int r = 0; r < 4; ++r)
        rmax[r] = fmaxf(rmax[r], __shfl_xor(rmax[r], off, 64));

    float fac[4], rsum[4];
#pragma unroll
    for (int r = 0; r < 4; ++r) {
      float mn = fmaxf(m[r], rmax[r]);
      fac[r] = exp2f((m[r] - mn) * LOG2E);
      m[r] = mn;
      rsum[r] = 0.0f;
    }
#pragma unroll
    for (int f = 0; f < 4; ++f)
#pragma unroll
      for (int r = 0; r < 4; ++r) {
        float pv = exp2f((s[f][r] - m[r]) * LOG2E);
        s[f][r] = pv;
        rsum[r] += pv;
      }
#pragma unroll
    for (int off = 1; off < 16; off <<= 1)
#pragma unroll
      for (int r = 0; r < 4; ++r)
        rsum[r] += __shfl_xor(rsum[r], off, 64);
#pragma unroll
    for (int r = 0; r < 4; ++r) l[r] = l[r] * fac[r] + rsum[r];
#pragma unroll
    for (int fh = 0; fh < 8; ++fh)
#pragma unroll
      for (int r = 0; r < 4; ++r) acc[fh][r] *= fac[r];

    // P -> LDS (C-frag layout) -> A-frag layout (wave-private, no barrier)
#pragma unroll
    for (int f = 0; f < 4; ++f)
#pragma unroll
      for (int r = 0; r < 4; ++r)
        *(unsigned short*)&plds[w][g * 4 + r][f * 16 + l15] = f2bf(s[f][r]);

    short8 pf0 = *(const short8*)&plds[w][l15][g * 8];
    short8 pf1 = *(const short8*)&plds[w][l15][32 + g * 8];

    // O += P V   (V^T rows are kv-contiguous)
#pragma unroll
    for (int fh = 0; fh < 8; ++fh) {
      const bf16_t* vr = vb + (size_t)(fh * 16 + l15) * T_SEQ + kt * 64 + g * 8;
      short8 vf0 = *(const short8*)(vr);
      short8 vf1 = *(const short8*)(vr + 32);
      acc[fh] = __builtin_amdgcn_mfma_f32_16x16x32_bf16(pf0, vf0, acc[fh], 0, 0, 0);
      acc[fh] = __builtin_amdgcn_mfma_f32_16x16x32_bf16(pf1, vf1, acc[fh], 0, 0, 0);
    }
  }

  float inv[4];
#pragma unroll
  for (int r = 0; r < 4; ++r) inv[r] = 1.0f / l[r];
#pragma unroll
  for (int fh = 0; fh < 8; ++fh)
#pragma unroll
    for (int r = 0; r < 4; ++r) {
      int tg = qt * 64 + w * 16 + g * 4 + r;
      attn[((size_t)b * T_SEQ + tg) * D_MODEL + (size_t)h * HEAD_DIM + fh * 16 + l15] =
          f2bf(acc[fh][r] * inv[r]);
    }
}

// ---------------- launch ----------------
extern "C" void kernel_launch(void* const* d_in, const int* in_sizes, int n_in,
                              void* d_out, int out_size, void* d_ws, size_t ws_size,
                              hipStream_t stream) {
  const float* x    = (const float*)d_in[0];
  const float* cosb = (const float*)d_in[1];
  const float* sinb = (const float*)d_in[2];
  const float* Wqkv = (const float*)d_in[3];
  const float* Wout = (const float*)d_in[4];
  float* out = (float*)d_out;

  char* ws = (char*)d_ws;
  size_t off = 0;
  bf16_t* xb    = (bf16_t*)(ws + off); off += (size_t)4096 * 2048 * 2;   // 16 MiB
  bf16_t* wqkvb = (bf16_t*)(ws + off); off += (size_t)6144 * 2048 * 2;   // 24 MiB
  bf16_t* woutb = (bf16_t*)(ws + off); off += (size_t)2048 * 2048 * 2;   //  8 MiB
  bf16_t* qkvb  = (bf16_t*)(ws + off); off += (size_t)4096 * 6144 * 2;   // 48 MiB
  bf16_t* qb    = (bf16_t*)(ws + off); off += (size_t)32 * 2048 * 128 * 2;
  bf16_t* kb    = (bf16_t*)(ws + off); off += (size_t)32 * 2048 * 128 * 2;
  bf16_t* vTb   = (bf16_t*)(ws + off); off += (size_t)32 * 2048 * 128 * 2;
  bf16_t* attnb = xb;  // xb dead after QKV GEMM; reuse as attention output
  // total ws required: 144 MiB

  cvt_kernel<<<8192, 256, 0, stream>>>(x, (unsigned short*)xb, 4096 * 2048 / 4);
  cvt_kernel<<<12288, 256, 0, stream>>>(Wqkv, (unsigned short*)wqkvb, 6144 * 2048 / 4);
  cvt_kernel<<<4096, 256, 0, stream>>>(Wout, (unsigned short*)woutb, 2048 * 2048 / 4);

  dim3 g1(48, 32);
  gemm_bt_kernel<0><<<g1, 256, 0, stream>>>(xb, wqkvb, nullptr, (unsigned short*)qkvb,
                                            4096, 6144, 2048);

  rope_kernel<<<1024, 256, 0, stream>>>(qkvb, cosb, sinb, qb, kb, vTb);

  attn_kernel<<<1024, 256, 0, stream>>>(qb, kb, vTb, (unsigned short*)attnb);

  dim3 g2(16, 32);
  gemm_bt_kernel<1><<<g2, 256, 0, stream>>>(attnb, woutb, out, nullptr,
                                            4096, 2048, 2048);
}

// Round 2
// 334.466 us; speedup vs baseline: 2.1769x; 2.1769x over previous
//
#include <hip/hip_runtime.h>
#include <hip/hip_bf16.h>
#include <stdint.h>

#define T_SEQ 2048
#define D_MODEL 2048
#define N_HEADS 16
#define HEAD_DIM 128

typedef __hip_bfloat16 bf16_t;
typedef __attribute__((ext_vector_type(8))) short short8;
typedef __attribute__((ext_vector_type(4))) short short4v;
typedef __attribute__((ext_vector_type(4))) float f32x4;

__device__ __forceinline__ unsigned short f2bf(float x) {
  union { float f; unsigned u; } c; c.f = x;
  unsigned u = c.u;
  u += 0x7fffu + ((u >> 16) & 1u);   // RNE
  return (unsigned short)(u >> 16);
}
__device__ __forceinline__ float bf2f(short v) {
  union { unsigned u; float f; } c;
  c.u = ((unsigned)(unsigned short)v) << 16;
  return c.f;
}
__device__ __forceinline__ void async16(const bf16_t* g, bf16_t* l) {
  __builtin_amdgcn_global_load_lds(
      (const __attribute__((address_space(1))) void*)g,
      (__attribute__((address_space(3))) void*)l, 16, 0, 0);
}

// ---------------- f32 -> bf16 conversion ----------------
__global__ __launch_bounds__(256) void cvt_kernel(const float* __restrict__ in,
                                                  unsigned short* __restrict__ out,
                                                  int n4) {
  int i = blockIdx.x * 256 + threadIdx.x;
  if (i >= n4) return;
  float4 v = ((const float4*)in)[i];
  short4v o;
  o[0] = (short)f2bf(v.x); o[1] = (short)f2bf(v.y);
  o[2] = (short)f2bf(v.z); o[3] = (short)f2bf(v.w);
  ((short4v*)out)[i] = o;
}

// ---------------- GEMM C[M,N] = A[M,K] * B[N,K]^T  (bf16 in, f32 acc) ----------------
// 128x128 tile, BK=32, 256 threads (4 waves 2x2), m97-style 2-barrier loop.
template<int F32OUT>
__global__ __launch_bounds__(256) void gemm_bt_kernel(
    const bf16_t* __restrict__ A, const bf16_t* __restrict__ Bm,
    float* __restrict__ Cf, unsigned short* __restrict__ Cb,
    int M, int N, int K) {
  __shared__ bf16_t As[128 * 32];
  __shared__ bf16_t Bs[128 * 32];
  const int tid = threadIdx.x;
  const int lane = tid & 63;
  const int wv = tid >> 6;
  const int wr = wv >> 1, wc = wv & 1;
  const int l15 = lane & 15, g = lane >> 4;
  const int m0 = blockIdx.y * 128, n0 = blockIdx.x * 128;

  const int srow = tid >> 2;          // 0..63
  const int scol = (tid & 3) << 3;    // 0,8,16,24

  f32x4 acc[4][4];
#pragma unroll
  for (int i = 0; i < 4; ++i)
#pragma unroll
    for (int j = 0; j < 4; ++j)
#pragma unroll
      for (int e = 0; e < 4; ++e) acc[i][j][e] = 0.0f;

  for (int k0 = 0; k0 < K; k0 += 32) {
    __syncthreads();
    const bf16_t* ag = A + (size_t)(m0 + srow) * K + k0 + scol;
    const bf16_t* bg = Bm + (size_t)(n0 + srow) * K + k0 + scol;
    bf16_t* al = As + wv * 512;   // wave-uniform LDS base; HW adds lane*16B
    bf16_t* bl = Bs + wv * 512;
    async16(ag, al);
    async16(ag + (size_t)64 * K, al + 2048);
    async16(bg, bl);
    async16(bg + (size_t)64 * K, bl + 2048);
    __syncthreads();   // compiler emits vmcnt(0) before barrier -> loads landed

    short8 af[4], bfr[4];
#pragma unroll
    for (int mi = 0; mi < 4; ++mi)
      af[mi] = *(const short8*)(As + (wr * 64 + mi * 16 + l15) * 32 + g * 8);
#pragma unroll
    for (int ni = 0; ni < 4; ++ni)
      bfr[ni] = *(const short8*)(Bs + (wc * 64 + ni * 16 + l15) * 32 + g * 8);
#pragma unroll
    for (int mi = 0; mi < 4; ++mi)
#pragma unroll
      for (int ni = 0; ni < 4; ++ni)
        acc[mi][ni] = __builtin_amdgcn_mfma_f32_16x16x32_bf16(af[mi], bfr[ni], acc[mi][ni], 0, 0, 0);
  }

#pragma unroll
  for (int mi = 0; mi < 4; ++mi)
#pragma unroll
    for (int ni = 0; ni < 4; ++ni)
#pragma unroll
      for (int r = 0; r < 4; ++r) {
        int mr = m0 + wr * 64 + mi * 16 + g * 4 + r;
        int nc = n0 + wc * 64 + ni * 16 + l15;
        if (F32OUT)
          Cf[(size_t)mr * N + nc] = acc[mi][ni][r];
        else
          Cb[(size_t)mr * N + nc] = f2bf(acc[mi][ni][r]);
      }
}

// ---------------- RoPE + split + V transpose ----------------
// qkv [B,T,3D] bf16 -> q,k [BH,T,HD] bf16 (q pre-scaled by 1/sqrt(HD)), vT [BH,HD,T] bf16
__global__ __launch_bounds__(256) void rope_kernel(
    const bf16_t* __restrict__ qkv,
    const float* __restrict__ cosb, const float* __restrict__ sinb,
    bf16_t* __restrict__ qo, bf16_t* __restrict__ ko, bf16_t* __restrict__ vT) {
  const int nTT = T_SEQ / 64;
  const int bx = blockIdx.x;
  const int bh = bx / nTT, tt = bx % nTT;
  const int b = bh / N_HEADS, h = bh % N_HEADS;
  const int tid = threadIdx.x;
  __shared__ bf16_t vlds[64][136];   // +8 pad breaks bank alignment on transpose read

  const float SC = 0.08838834764831845f;  // 1/sqrt(128)

#pragma unroll
  for (int it = 0; it < 2; ++it) {
    int item = it * 256 + tid;      // 0..511
    int r = item >> 3, cg = item & 7;
    int t = tt * 64 + r;
    int c0 = cg * 8;                // hd offset in first half [0,64)
    size_t base = ((size_t)b * T_SEQ + t) * (size_t)(3 * D_MODEL) + (size_t)h * HEAD_DIM;

    float cs0[8], sn0[8], cs1[8], sn1[8];
    {
      const float* cp = cosb + (size_t)t * HEAD_DIM + c0;
      const float* sp = sinb + (size_t)t * HEAD_DIM + c0;
      float4 a0 = *(const float4*)(cp), a1 = *(const float4*)(cp + 4);
      float4 b0 = *(const float4*)(cp + 64), b1 = *(const float4*)(cp + 68);
      float4 s0 = *(const float4*)(sp), s1 = *(const float4*)(sp + 4);
      float4 t0 = *(const float4*)(sp + 64), t1 = *(const float4*)(sp + 68);
      cs0[0]=a0.x; cs0[1]=a0.y; cs0[2]=a0.z; cs0[3]=a0.w; cs0[4]=a1.x; cs0[5]=a1.y; cs0[6]=a1.z; cs0[7]=a1.w;
      cs1[0]=b0.x; cs1[1]=b0.y; cs1[2]=b0.z; cs1[3]=b0.w; cs1[4]=b1.x; cs1[5]=b1.y; cs1[6]=b1.z; cs1[7]=b1.w;
      sn0[0]=s0.x; sn0[1]=s0.y; sn0[2]=s0.z; sn0[3]=s0.w; sn0[4]=s1.x; sn0[5]=s1.y; sn0[6]=s1.z; sn0[7]=s1.w;
      sn1[0]=t0.x; sn1[1]=t0.y; sn1[2]=t0.z; sn1[3]=t0.w; sn1[4]=t1.x; sn1[5]=t1.y; sn1[6]=t1.z; sn1[7]=t1.w;
    }

    // Q (scaled) and K (unscaled)
#pragma unroll
    for (int sec = 0; sec < 2; ++sec) {
      size_t sbase = base + (size_t)sec * D_MODEL;
      short8 lo = *(const short8*)(qkv + sbase + c0);
      short8 hi = *(const short8*)(qkv + sbase + 64 + c0);
      short8 olo, ohi;
#pragma unroll
      for (int e = 0; e < 8; ++e) {
        float xl = bf2f(lo[e]), xh = bf2f(hi[e]);
        float rl = xl * cs0[e] - xh * sn0[e];
        float rh = xh * cs1[e] + xl * sn1[e];
        if (sec == 0) { rl *= SC; rh *= SC; }
        olo[e] = (short)f2bf(rl);
        ohi[e] = (short)f2bf(rh);
      }
      bf16_t* dst = (sec == 0 ? qo : ko) + ((size_t)bh * T_SEQ + t) * HEAD_DIM + c0;
      *(short8*)dst = olo;
      *(short8*)(dst + 64) = ohi;
    }

    // V into LDS (row-major tile)
    short8 v0 = *(const short8*)(qkv + base + 2 * D_MODEL + c0);
    short8 v1 = *(const short8*)(qkv + base + 2 * D_MODEL + 64 + c0);
    *(short8*)&vlds[r][c0] = v0;
    *(short8*)&vlds[r][64 + c0] = v1;
  }
  __syncthreads();

  // transposed write: vT[bh][hd][t], 64B contiguous per thread
  int hd = tid >> 1, hf = tid & 1;
  bf16_t* dst = vT + ((size_t)bh * HEAD_DIM + hd) * T_SEQ + tt * 64 + hf * 32;
#pragma unroll
  for (int jj = 0; jj < 4; ++jj) {
    short8 o;
#pragma unroll
    for (int e = 0; e < 8; ++e)
      o[e] = *(const short*)&vlds[hf * 32 + jj * 8 + e][hd];
    *(short8*)(dst + jj * 8) = o;
  }
}

// ---------------- causal flash attention, LDS-staged double-buffered ----------------
// q,k [BH,T,HD] (q pre-scaled), vT [BH,HD,T] -> attn [B,T,D] bf16
// K tile [64][128] and V^T tile [128][64] staged via global_load_lds with
// chunk-XOR swizzle (chunk ^= row&7) applied on the GLOBAL source (rule #21).
__global__ __launch_bounds__(256) void attn_kernel(
    const bf16_t* __restrict__ q, const bf16_t* __restrict__ k,
    const bf16_t* __restrict__ vT, unsigned short* __restrict__ attn) {
  const int bx = blockIdx.x;
  const int bh = bx & 31;            // bx%8 == bh%8 -> one head's blocks share an XCD
  const int qt = 31 - (bx >> 5);     // qt-major, longest blocks dispatch first
  const int b = bh / N_HEADS, h = bh % N_HEADS;
  const int tid = threadIdx.x;
  const int w = tid >> 6, lane = tid & 63;
  const int l15 = lane & 15, g = lane >> 4;
  const float LOG2E = 1.44269504088896340736f;

  __shared__ bf16_t Ks[2][64 * 128];   // 2 x 16 KB
  __shared__ bf16_t Vs[2][128 * 64];   // 2 x 16 KB
  __shared__ bf16_t plds[4][16][72];   // per-wave P buffer

  const bf16_t* qb = q + (size_t)bh * T_SEQ * HEAD_DIM;
  const bf16_t* kb = k + (size_t)bh * T_SEQ * HEAD_DIM;
  const bf16_t* vb = vT + (size_t)bh * HEAD_DIM * T_SEQ;

  const int qrow = qt * 64 + w * 16 + l15;
  short8 qf[4];
#pragma unroll
  for (int kk = 0; kk < 4; ++kk)
    qf[kk] = *(const short8*)(qb + (size_t)qrow * HEAD_DIM + kk * 32 + g * 8);

  float m[4], l[4];
  f32x4 acc[8];
#pragma unroll
  for (int r = 0; r < 4; ++r) { m[r] = -3.0e38f; l[r] = 0.0f; }
#pragma unroll
  for (int fh = 0; fh < 8; ++fh)
#pragma unroll
    for (int e = 0; e < 4; ++e) acc[fh][e] = 0.0f;

  // ---- staging: wave w handles slabs {w, w+4, w+8, w+12} of 1KB each ----
  // K slab s: rows s*4..s*4+3 (256B rows, 16 chunks); lane i -> row s*4+i/16,
  //   LDS chunk i%16, GLOBAL chunk (i%16)^(row&7).
  // V slab s: rows s*8..s*8+7 (128B rows, 8 chunks); lane i -> row s*8+i/8,
  //   LDS chunk i%8, GLOBAL chunk (i%8)^(row&7).
#define STAGE_TILES(KT, BU)                                                      \
  {                                                                              \
    _Pragma("unroll")                                                            \
    for (int j = 0; j < 4; ++j) {                                                \
      int s = j * 4 + w;                                                         \
      int row = s * 4 + (lane >> 4);                                             \
      int gc = (lane & 15) ^ (row & 7);                                          \
      async16(kb + (size_t)((KT) * 64 + row) * HEAD_DIM + gc * 8,                \
              &Ks[BU][s * 512]);                                                 \
    }                                                                            \
    _Pragma("unroll")                                                            \
    for (int j = 0; j < 4; ++j) {                                                \
      int s = j * 4 + w;                                                         \
      int row = s * 8 + (lane >> 3);                                             \
      int gc = (lane & 7) ^ (row & 7);                                           \
      async16(vb + (size_t)row * T_SEQ + (KT) * 64 + gc * 8,                     \
              &Vs[BU][s * 512]);                                                 \
    }                                                                            \
  }

  STAGE_TILES(0, 0);
  __syncthreads();
  int buf = 0;

  for (int kt = 0; kt <= qt; ++kt) {
    if (kt < qt) STAGE_TILES(kt + 1, buf ^ 1);

    // ---- S = Q K^T (swizzled LDS read: 2-way banks, free) ----
    f32x4 s[4];
#pragma unroll
    for (int f = 0; f < 4; ++f)
#pragma unroll
      for (int e = 0; e < 4; ++e) s[f][e] = 0.0f;
    __builtin_amdgcn_s_setprio(1);
#pragma unroll
    for (int f = 0; f < 4; ++f) {
      int row = f * 16 + l15;
      int r7 = l15 & 7;
#pragma unroll
      for (int kk = 0; kk < 4; ++kk) {
        short8 kf = *(const short8*)(&Ks[buf][row * 128 + (((kk * 4 + g) ^ r7) << 3)]);
        s[f] = __builtin_amdgcn_mfma_f32_16x16x32_bf16(qf[kk], kf, s[f], 0, 0, 0);
      }
    }
    __builtin_amdgcn_s_setprio(0);

    if (kt == qt) {   // diagonal tile causal mask
#pragma unroll
      for (int f = 0; f < 4; ++f) {
        int kv = f * 16 + l15;
#pragma unroll
        for (int r = 0; r < 4; ++r) {
          int qq = w * 16 + g * 4 + r;
          if (kv > qq) s[f][r] = -3.0e38f;
        }
      }
    }
    // ---- online softmax (rows in 16-lane groups) ----
    float rmax[4];
#pragma unroll
    for (int r = 0; r < 4; ++r)
      rmax[r] = fmaxf(fmaxf(s[0][r], s[1][r]), fmaxf(s[2][r], s[3][r]));
#pragma unroll
    for (int off = 1; off < 16; off <<= 1)
#pragma unroll
      for (int r = 0; r < 4; ++r)
        rmax[r] = fmaxf(rmax[r], __shfl_xor(rmax[r], off, 64));

    float fac[4], rsum[4];
#pragma unroll
    for (int r = 0; r < 4; ++r) {
      float mn = fmaxf(m[r], rmax[r]);
      fac[r] = exp2f((m[r] - mn) * LOG2E);
      m[r] = mn;
      rsum[r] = 0.0f;
    }
#pragma unroll
    for (int f = 0; f < 4; ++f)
#pragma unroll
      for (int r = 0; r < 4; ++r) {
        float pv = exp2f((s[f][r] - m[r]) * LOG2E);
        s[f][r] = pv;
        rsum[r] += pv;
      }
#pragma unroll
    for (int off = 1; off < 16; off <<= 1)
#pragma unroll
      for (int r = 0; r < 4; ++r)
        rsum[r] += __shfl_xor(rsum[r], off, 64);
#pragma unroll
    for (int r = 0; r < 4; ++r) l[r] = l[r] * fac[r] + rsum[r];
#pragma unroll
    for (int fh = 0; fh < 8; ++fh)
#pragma unroll
      for (int r = 0; r < 4; ++r) acc[fh][r] *= fac[r];

    // ---- P -> LDS (C-frag) -> A-frag (wave-private, no barrier) ----
#pragma unroll
    for (int f = 0; f < 4; ++f)
#pragma unroll
      for (int r = 0; r < 4; ++r)
        *(unsigned short*)&plds[w][g * 4 + r][f * 16 + l15] = f2bf(s[f][r]);

    short8 pf0 = *(const short8*)&plds[w][l15][g * 8];
    short8 pf1 = *(const short8*)&plds[w][l15][32 + g * 8];

    // ---- O += P V (V^T rows kv-contiguous, swizzled read) ----
    __builtin_amdgcn_s_setprio(1);
#pragma unroll
    for (int fh = 0; fh < 8; ++fh) {
      int row = fh * 16 + l15;
      int r7 = l15 & 7;
      short8 vf0 = *(const short8*)(&Vs[buf][row * 64 + ((g ^ r7) << 3)]);
      short8 vf1 = *(const short8*)(&Vs[buf][row * 64 + (((4 + g) ^ r7) << 3)]);
      acc[fh] = __builtin_amdgcn_mfma_f32_16x16x32_bf16(pf0, vf0, acc[fh], 0, 0, 0);
      acc[fh] = __builtin_amdgcn_mfma_f32_16x16x32_bf16(pf1, vf1, acc[fh], 0, 0, 0);
    }
    __builtin_amdgcn_s_setprio(0);

    __syncthreads();   // drains vmcnt (next tile landed) + all waves done with buf
    buf ^= 1;
  }

  float inv[4];
#pragma unroll
  for (int r = 0; r < 4; ++r) inv[r] = 1.0f / l[r];
#pragma unroll
  for (int fh = 0; fh < 8; ++fh)
#pragma unroll
    for (int r = 0; r < 4; ++r) {
      int tg = qt * 64 + w * 16 + g * 4 + r;
      attn[((size_t)b * T_SEQ + tg) * D_MODEL + (size_t)h * HEAD_DIM + fh * 16 + l15] =
          f2bf(acc[fh][r] * inv[r]);
    }
}

// ---------------- launch ----------------
extern "C" void kernel_launch(void* const* d_in, const int* in_sizes, int n_in,
                              void* d_out, int out_size, void* d_ws, size_t ws_size,
                              hipStream_t stream) {
  const float* x    = (const float*)d_in[0];
  const float* cosb = (const float*)d_in[1];
  const float* sinb = (const float*)d_in[2];
  const float* Wqkv = (const float*)d_in[3];
  const float* Wout = (const float*)d_in[4];
  float* out = (float*)d_out;

  char* ws = (char*)d_ws;
  size_t off = 0;
  bf16_t* xb    = (bf16_t*)(ws + off); off += (size_t)4096 * 2048 * 2;   // 16 MiB
  bf16_t* wqkvb = (bf16_t*)(ws + off); off += (size_t)6144 * 2048 * 2;   // 24 MiB
  bf16_t* woutb = (bf16_t*)(ws + off); off += (size_t)2048 * 2048 * 2;   //  8 MiB
  bf16_t* qkvb  = (bf16_t*)(ws + off); off += (size_t)4096 * 6144 * 2;   // 48 MiB
  bf16_t* qb    = (bf16_t*)(ws + off); off += (size_t)32 * 2048 * 128 * 2;
  bf16_t* kb    = (bf16_t*)(ws + off); off += (size_t)32 * 2048 * 128 * 2;
  bf16_t* vTb   = (bf16_t*)(ws + off); off += (size_t)32 * 2048 * 128 * 2;
  bf16_t* attnb = xb;  // xb dead after QKV GEMM; reuse as attention output
  // total ws required: 144 MiB

  cvt_kernel<<<8192, 256, 0, stream>>>(x, (unsigned short*)xb, 4096 * 2048 / 4);
  cvt_kernel<<<12288, 256, 0, stream>>>(Wqkv, (unsigned short*)wqkvb, 6144 * 2048 / 4);
  cvt_kernel<<<4096, 256, 0, stream>>>(Wout, (unsigned short*)woutb, 2048 * 2048 / 4);

  dim3 g1(48, 32);
  gemm_bt_kernel<0><<<g1, 256, 0, stream>>>(xb, wqkvb, nullptr, (unsigned short*)qkvb,
                                            4096, 6144, 2048);

  rope_kernel<<<1024, 256, 0, stream>>>(qkvb, cosb, sinb, qb, kb, vTb);

  attn_kernel<<<1024, 256, 0, stream>>>(qb, kb, vTb, (unsigned short*)attnb);

  dim3 g2(16, 32);
  gemm_bt_kernel<1><<<g2, 256, 0, stream>>>(attnb, woutb, out, nullptr,
                                            4096, 2048, 2048);
}

// Round 3
// 325.005 us; speedup vs baseline: 2.2403x; 1.0291x over previous
//
#include <hip/hip_runtime.h>
#include <hip/hip_bf16.h>
#include <stdint.h>

#define T_SEQ 2048
#define D_MODEL 2048
#define N_HEADS 16
#define HEAD_DIM 128

typedef __hip_bfloat16 bf16_t;
typedef __attribute__((ext_vector_type(8))) short short8;
typedef __attribute__((ext_vector_type(4))) short short4v;
typedef __attribute__((ext_vector_type(4))) float f32x4;

__device__ __forceinline__ unsigned short f2bf(float x) {
  union { float f; unsigned u; } c; c.f = x;
  unsigned u = c.u;
  u += 0x7fffu + ((u >> 16) & 1u);   // RNE
  return (unsigned short)(u >> 16);
}
__device__ __forceinline__ float bf2f(short v) {
  union { unsigned u; float f; } c;
  c.u = ((unsigned)(unsigned short)v) << 16;
  return c.f;
}
__device__ __forceinline__ void async16(const bf16_t* g, bf16_t* l) {
  __builtin_amdgcn_global_load_lds(
      (const __attribute__((address_space(1))) void*)g,
      (__attribute__((address_space(3))) void*)l, 16, 0, 0);
}

// ---------------- f32 -> bf16 conversion ----------------
__global__ __launch_bounds__(256) void cvt_kernel(const float* __restrict__ in,
                                                  unsigned short* __restrict__ out,
                                                  int n4) {
  int i = blockIdx.x * 256 + threadIdx.x;
  if (i >= n4) return;
  float4 v = ((const float4*)in)[i];
  short4v o;
  o[0] = (short)f2bf(v.x); o[1] = (short)f2bf(v.y);
  o[2] = (short)f2bf(v.z); o[3] = (short)f2bf(v.w);
  ((short4v*)out)[i] = o;
}

// ---------------- GEMM C[M,N] = A[M,K] * B[N,K]^T, 256x256 tile, phased ----------------
// 512 threads = 8 waves (2M x 4N); per-wave 128x64 output = acc[8][4] f32x4.
// BK=64; LDS = 2 buffers x (A 256x64 + B 256x64) bf16 = 128 KB.
// T2: chunk-XOR swizzle (chunk ^= row&7), inverse-swizzled global source,
//     linear global_load_lds dest, swizzled ds_read.
// T3/T4: 4 phases/K-tile {stage || ds_read || barrier || MFMA || barrier},
//        prefetch kt+1 issued phases 0-1, vmcnt(0) only at K-tile boundary.
// T5: setprio(1) around MFMA clusters.
template<int F32OUT>
__global__ __launch_bounds__(512, 2) void gemm8p_kernel(
    const bf16_t* __restrict__ A, const bf16_t* __restrict__ Bm,
    float* __restrict__ Cf, unsigned short* __restrict__ Cb,
    int M, int N, int K, int nbn) {
  __shared__ bf16_t lds[65536];   // 128 KB
  const int tid = threadIdx.x;
  const int w = tid >> 6, lane = tid & 63;
  const int wm = w >> 2, wn = w & 3;
  const int l15 = lane & 15, g = lane >> 4;

  // XCD-bijective swizzle (gridDim.x % 8 == 0 in all launches here)
  const int nwg = gridDim.x;
  const int cpx = nwg >> 3;
  const int wg = (blockIdx.x & 7) * cpx + (blockIdx.x >> 3);
  const int bm0 = (wg / nbn) * 256, bn0 = (wg % nbn) * 256;

  // staging: thread handles chunk (tid) and (tid+512) of each 128x64 half-tile
  const int srow = tid >> 3;                 // 0..63
  const int sgc = (tid & 7) ^ (srow & 7);    // pre-swizzled global chunk
  const bf16_t* agA = A + (size_t)(bm0 + srow) * K + sgc * 8;
  const bf16_t* agB = Bm + (size_t)(bn0 + srow) * K + sgc * 8;

#define STAGE_A(KT, BB) do {                                                  \
    _Pragma("unroll")                                                         \
    for (int h = 0; h < 2; ++h)                                               \
      _Pragma("unroll")                                                       \
      for (int j = 0; j < 2; ++j)                                             \
        async16(agA + (size_t)(h * 128 + j * 64) * K + (size_t)(KT) * 64,     \
                lds + (BB) * 32768 + h * 8192 + (j * 512 + w * 64) * 8);      \
  } while (0)
#define STAGE_B(KT, BB) do {                                                  \
    _Pragma("unroll")                                                         \
    for (int h = 0; h < 2; ++h)                                               \
      _Pragma("unroll")                                                       \
      for (int j = 0; j < 2; ++j)                                             \
        async16(agB + (size_t)(h * 128 + j * 64) * K + (size_t)(KT) * 64,     \
                lds + (BB) * 32768 + 16384 + h * 8192 + (j * 512 + w * 64) * 8); \
  } while (0)

  // swizzled chunk byte offsets (element units) for kk=0 / kk=1
  const int swlo = ((g) ^ (l15 & 7)) * 8;
  const int swhi = ((4 + g) ^ (l15 & 7)) * 8;

  f32x4 acc[8][4];
#pragma unroll
  for (int i = 0; i < 8; ++i)
#pragma unroll
    for (int j = 0; j < 4; ++j)
#pragma unroll
      for (int e = 0; e < 4; ++e) acc[i][j][e] = 0.0f;

  STAGE_A(0, 0);
  STAGE_B(0, 0);
  asm volatile("s_waitcnt vmcnt(0)" ::: "memory");
  __builtin_amdgcn_s_barrier();

  const int NT = K >> 6;
  for (int kt = 0; kt < NT; ++kt) {
    const int bb = kt & 1;
    const bool pf = (kt + 1 < NT);
    const bf16_t* As_ = lds + bb * 32768 + wm * 8192 + l15 * 64;
    const bf16_t* Bs_ = lds + bb * 32768 + 16384 + (wn >> 1) * 8192 +
                        ((wn & 1) * 64 + l15) * 64;

#define LDA(mi, kk) (*(const short8*)(As_ + (mi) * 1024 + ((kk) ? swhi : swlo)))
#define LDB(ni, kk) (*(const short8*)(Bs_ + (ni) * 1024 + ((kk) ? swhi : swlo)))

    short8 af[4][2], b01[2][2], b23[2][2];

    // ---- phase 0: stage A(kt+1); read A[qm0], B[ni0,1]; MFMA qm0 x ni01 ----
    if (pf) STAGE_A(kt + 1, bb ^ 1);
#pragma unroll
    for (int i = 0; i < 4; ++i) { af[i][0] = LDA(i, 0); af[i][1] = LDA(i, 1); }
#pragma unroll
    for (int n = 0; n < 2; ++n) { b01[n][0] = LDB(n, 0); b01[n][1] = LDB(n, 1); }
    __builtin_amdgcn_s_barrier();
    __builtin_amdgcn_s_setprio(1);
#pragma unroll
    for (int i = 0; i < 4; ++i)
#pragma unroll
      for (int n = 0; n < 2; ++n) {
        acc[i][n] = __builtin_amdgcn_mfma_f32_16x16x32_bf16(af[i][0], b01[n][0], acc[i][n], 0, 0, 0);
        acc[i][n] = __builtin_amdgcn_mfma_f32_16x16x32_bf16(af[i][1], b01[n][1], acc[i][n], 0, 0, 0);
      }
    __builtin_amdgcn_s_setprio(0);
    __builtin_amdgcn_s_barrier();

    // ---- phase 1: stage B(kt+1); read B[ni2,3]; MFMA qm0 x ni23 ----
    if (pf) STAGE_B(kt + 1, bb ^ 1);
#pragma unroll
    for (int n = 0; n < 2; ++n) { b23[n][0] = LDB(2 + n, 0); b23[n][1] = LDB(2 + n, 1); }
    __builtin_amdgcn_s_barrier();
    __builtin_amdgcn_s_setprio(1);
#pragma unroll
    for (int i = 0; i < 4; ++i)
#pragma unroll
      for (int n = 0; n < 2; ++n) {
        acc[i][2 + n] = __builtin_amdgcn_mfma_f32_16x16x32_bf16(af[i][0], b23[n][0], acc[i][2 + n], 0, 0, 0);
        acc[i][2 + n] = __builtin_amdgcn_mfma_f32_16x16x32_bf16(af[i][1], b23[n][1], acc[i][2 + n], 0, 0, 0);
      }
    __builtin_amdgcn_s_setprio(0);
    __builtin_amdgcn_s_barrier();

    // ---- phase 2: read A[qm1]; MFMA qm1 x ni01 ----
#pragma unroll
    for (int i = 0; i < 4; ++i) { af[i][0] = LDA(4 + i, 0); af[i][1] = LDA(4 + i, 1); }
    __builtin_amdgcn_s_barrier();
    __builtin_amdgcn_s_setprio(1);
#pragma unroll
    for (int i = 0; i < 4; ++i)
#pragma unroll
      for (int n = 0; n < 2; ++n) {
        acc[4 + i][n] = __builtin_amdgcn_mfma_f32_16x16x32_bf16(af[i][0], b01[n][0], acc[4 + i][n], 0, 0, 0);
        acc[4 + i][n] = __builtin_amdgcn_mfma_f32_16x16x32_bf16(af[i][1], b01[n][1], acc[4 + i][n], 0, 0, 0);
      }
    __builtin_amdgcn_s_setprio(0);
    __builtin_amdgcn_s_barrier();

    // ---- phase 3: MFMA qm1 x ni23 (registers only) ----
    __builtin_amdgcn_s_setprio(1);
#pragma unroll
    for (int i = 0; i < 4; ++i)
#pragma unroll
      for (int n = 0; n < 2; ++n) {
        acc[4 + i][2 + n] = __builtin_amdgcn_mfma_f32_16x16x32_bf16(af[i][0], b23[n][0], acc[4 + i][2 + n], 0, 0, 0);
        acc[4 + i][2 + n] = __builtin_amdgcn_mfma_f32_16x16x32_bf16(af[i][1], b23[n][1], acc[4 + i][2 + n], 0, 0, 0);
      }
    __builtin_amdgcn_s_setprio(0);

    // ---- K-tile boundary: wait own prefetch, then all waves sync ----
    if (pf) asm volatile("s_waitcnt vmcnt(0)" ::: "memory");
    __builtin_amdgcn_s_barrier();
#undef LDA
#undef LDB
  }

  // ---- epilogue ----
#pragma unroll
  for (int mi = 0; mi < 8; ++mi)
#pragma unroll
    for (int ni = 0; ni < 4; ++ni)
#pragma unroll
      for (int r = 0; r < 4; ++r) {
        int mr = bm0 + wm * 128 + mi * 16 + g * 4 + r;
        int nc = bn0 + wn * 64 + ni * 16 + l15;
        if (F32OUT)
          Cf[(size_t)mr * N + nc] = acc[mi][ni][r];
        else
          Cb[(size_t)mr * N + nc] = f2bf(acc[mi][ni][r]);
      }
#undef STAGE_A
#undef STAGE_B
}

// ---------------- RoPE + split + V transpose ----------------
__global__ __launch_bounds__(256) void rope_kernel(
    const bf16_t* __restrict__ qkv,
    const float* __restrict__ cosb, const float* __restrict__ sinb,
    bf16_t* __restrict__ qo, bf16_t* __restrict__ ko, bf16_t* __restrict__ vT) {
  const int nTT = T_SEQ / 64;
  const int bx = blockIdx.x;
  const int bh = bx / nTT, tt = bx % nTT;
  const int b = bh / N_HEADS, h = bh % N_HEADS;
  const int tid = threadIdx.x;
  __shared__ bf16_t vlds[64][136];

  const float SC = 0.08838834764831845f;  // 1/sqrt(128)

#pragma unroll
  for (int it = 0; it < 2; ++it) {
    int item = it * 256 + tid;
    int r = item >> 3, cg = item & 7;
    int t = tt * 64 + r;
    int c0 = cg * 8;
    size_t base = ((size_t)b * T_SEQ + t) * (size_t)(3 * D_MODEL) + (size_t)h * HEAD_DIM;

    float cs0[8], sn0[8], cs1[8], sn1[8];
    {
      const float* cp = cosb + (size_t)t * HEAD_DIM + c0;
      const float* sp = sinb + (size_t)t * HEAD_DIM + c0;
      float4 a0 = *(const float4*)(cp), a1 = *(const float4*)(cp + 4);
      float4 b0 = *(const float4*)(cp + 64), b1 = *(const float4*)(cp + 68);
      float4 s0 = *(const float4*)(sp), s1 = *(const float4*)(sp + 4);
      float4 t0 = *(const float4*)(sp + 64), t1 = *(const float4*)(sp + 68);
      cs0[0]=a0.x; cs0[1]=a0.y; cs0[2]=a0.z; cs0[3]=a0.w; cs0[4]=a1.x; cs0[5]=a1.y; cs0[6]=a1.z; cs0[7]=a1.w;
      cs1[0]=b0.x; cs1[1]=b0.y; cs1[2]=b0.z; cs1[3]=b0.w; cs1[4]=b1.x; cs1[5]=b1.y; cs1[6]=b1.z; cs1[7]=b1.w;
      sn0[0]=s0.x; sn0[1]=s0.y; sn0[2]=s0.z; sn0[3]=s0.w; sn0[4]=s1.x; sn0[5]=s1.y; sn0[6]=s1.z; sn0[7]=s1.w;
      sn1[0]=t0.x; sn1[1]=t0.y; sn1[2]=t0.z; sn1[3]=t0.w; sn1[4]=t1.x; sn1[5]=t1.y; sn1[6]=t1.z; sn1[7]=t1.w;
    }

#pragma unroll
    for (int sec = 0; sec < 2; ++sec) {
      size_t sbase = base + (size_t)sec * D_MODEL;
      short8 lo = *(const short8*)(qkv + sbase + c0);
      short8 hi = *(const short8*)(qkv + sbase + 64 + c0);
      short8 olo, ohi;
#pragma unroll
      for (int e = 0; e < 8; ++e) {
        float xl = bf2f(lo[e]), xh = bf2f(hi[e]);
        float rl = xl * cs0[e] - xh * sn0[e];
        float rh = xh * cs1[e] + xl * sn1[e];
        if (sec == 0) { rl *= SC; rh *= SC; }
        olo[e] = (short)f2bf(rl);
        ohi[e] = (short)f2bf(rh);
      }
      bf16_t* dst = (sec == 0 ? qo : ko) + ((size_t)bh * T_SEQ + t) * HEAD_DIM + c0;
      *(short8*)dst = olo;
      *(short8*)(dst + 64) = ohi;
    }

    short8 v0 = *(const short8*)(qkv + base + 2 * D_MODEL + c0);
    short8 v1 = *(const short8*)(qkv + base + 2 * D_MODEL + 64 + c0);
    *(short8*)&vlds[r][c0] = v0;
    *(short8*)&vlds[r][64 + c0] = v1;
  }
  __syncthreads();

  int hd = tid >> 1, hf = tid & 1;
  bf16_t* dst = vT + ((size_t)bh * HEAD_DIM + hd) * T_SEQ + tt * 64 + hf * 32;
#pragma unroll
  for (int jj = 0; jj < 4; ++jj) {
    short8 o;
#pragma unroll
    for (int e = 0; e < 8; ++e)
      o[e] = *(const short*)&vlds[hf * 32 + jj * 8 + e][hd];
    *(short8*)(dst + jj * 8) = o;
  }
}

// ---------------- causal flash attention, LDS-staged double-buffered ----------------
__global__ __launch_bounds__(256) void attn_kernel(
    const bf16_t* __restrict__ q, const bf16_t* __restrict__ k,
    const bf16_t* __restrict__ vT, unsigned short* __restrict__ attn) {
  const int bx = blockIdx.x;
  const int bh = bx & 31;
  const int qt = 31 - (bx >> 5);
  const int b = bh / N_HEADS, h = bh % N_HEADS;
  const int tid = threadIdx.x;
  const int w = tid >> 6, lane = tid & 63;
  const int l15 = lane & 15, g = lane >> 4;
  const float LOG2E = 1.44269504088896340736f;

  __shared__ bf16_t Ks[2][64 * 128];
  __shared__ bf16_t Vs[2][128 * 64];
  __shared__ bf16_t plds[4][16][72];

  const bf16_t* qb = q + (size_t)bh * T_SEQ * HEAD_DIM;
  const bf16_t* kb = k + (size_t)bh * T_SEQ * HEAD_DIM;
  const bf16_t* vb = vT + (size_t)bh * HEAD_DIM * T_SEQ;

  const int qrow = qt * 64 + w * 16 + l15;
  short8 qf[4];
#pragma unroll
  for (int kk = 0; kk < 4; ++kk)
    qf[kk] = *(const short8*)(qb + (size_t)qrow * HEAD_DIM + kk * 32 + g * 8);

  float m[4], l[4];
  f32x4 acc[8];
#pragma unroll
  for (int r = 0; r < 4; ++r) { m[r] = -3.0e38f; l[r] = 0.0f; }
#pragma unroll
  for (int fh = 0; fh < 8; ++fh)
#pragma unroll
    for (int e = 0; e < 4; ++e) acc[fh][e] = 0.0f;

#define STAGE_TILES(KT, BU)                                                      \
  {                                                                              \
    _Pragma("unroll")                                                            \
    for (int j = 0; j < 4; ++j) {                                                \
      int s = j * 4 + w;                                                         \
      int row = s * 4 + (lane >> 4);                                             \
      int gc = (lane & 15) ^ (row & 7);                                          \
      async16(kb + (size_t)((KT) * 64 + row) * HEAD_DIM + gc * 8,                \
              &Ks[BU][s * 512]);                                                 \
    }                                                                            \
    _Pragma("unroll")                                                            \
    for (int j = 0; j < 4; ++j) {                                                \
      int s = j * 4 + w;                                                         \
      int row = s * 8 + (lane >> 3);                                             \
      int gc = (lane & 7) ^ (row & 7);                                           \
      async16(vb + (size_t)row * T_SEQ + (KT) * 64 + gc * 8,                     \
              &Vs[BU][s * 512]);                                                 \
    }                                                                            \
  }

  STAGE_TILES(0, 0);
  __syncthreads();
  int buf = 0;

  for (int kt = 0; kt <= qt; ++kt) {
    if (kt < qt) STAGE_TILES(kt + 1, buf ^ 1);

    f32x4 s[4];
#pragma unroll
    for (int f = 0; f < 4; ++f)
#pragma unroll
      for (int e = 0; e < 4; ++e) s[f][e] = 0.0f;
    __builtin_amdgcn_s_setprio(1);
#pragma unroll
    for (int f = 0; f < 4; ++f) {
      int row = f * 16 + l15;
      int r7 = l15 & 7;
#pragma unroll
      for (int kk = 0; kk < 4; ++kk) {
        short8 kf = *(const short8*)(&Ks[buf][row * 128 + (((kk * 4 + g) ^ r7) << 3)]);
        s[f] = __builtin_amdgcn_mfma_f32_16x16x32_bf16(qf[kk], kf, s[f], 0, 0, 0);
      }
    }
    __builtin_amdgcn_s_setprio(0);

    if (kt == qt) {
#pragma unroll
      for (int f = 0; f < 4; ++f) {
        int kv = f * 16 + l15;
#pragma unroll
        for (int r = 0; r < 4; ++r) {
          int qq = w * 16 + g * 4 + r;
          if (kv > qq) s[f][r] = -3.0e38f;
        }
      }
    }
    float rmax[4];
#pragma unroll
    for (int r = 0; r < 4; ++r)
      rmax[r] = fmaxf(fmaxf(s[0][r], s[1][r]), fmaxf(s[2][r], s[3][r]));
#pragma unroll
    for (int off = 1; off < 16; off <<= 1)
#pragma unroll
      for (int r = 0; r < 4; ++r)
        rmax[r] = fmaxf(rmax[r], __shfl_xor(rmax[r], off, 64));

    float fac[4], rsum[4];
#pragma unroll
    for (int r = 0; r < 4; ++r) {
      float mn = fmaxf(m[r], rmax[r]);
      fac[r] = exp2f((m[r] - mn) * LOG2E);
      m[r] = mn;
      rsum[r] = 0.0f;
    }
#pragma unroll
    for (int f = 0; f < 4; ++f)
#pragma unroll
      for (int r = 0; r < 4; ++r) {
        float pv = exp2f((s[f][r] - m[r]) * LOG2E);
        s[f][r] = pv;
        rsum[r] += pv;
      }
#pragma unroll
    for (int off = 1; off < 16; off <<= 1)
#pragma unroll
      for (int r = 0; r < 4; ++r)
        rsum[r] += __shfl_xor(rsum[r], off, 64);
#pragma unroll
    for (int r = 0; r < 4; ++r) l[r] = l[r] * fac[r] + rsum[r];
#pragma unroll
    for (int fh = 0; fh < 8; ++fh)
#pragma unroll
      for (int r = 0; r < 4; ++r) acc[fh][r] *= fac[r];

#pragma unroll
    for (int f = 0; f < 4; ++f)
#pragma unroll
      for (int r = 0; r < 4; ++r)
        *(unsigned short*)&plds[w][g * 4 + r][f * 16 + l15] = f2bf(s[f][r]);

    short8 pf0 = *(const short8*)&plds[w][l15][g * 8];
    short8 pf1 = *(const short8*)&plds[w][l15][32 + g * 8];

    __builtin_amdgcn_s_setprio(1);
#pragma unroll
    for (int fh = 0; fh < 8; ++fh) {
      int row = fh * 16 + l15;
      int r7 = l15 & 7;
      short8 vf0 = *(const short8*)(&Vs[buf][row * 64 + ((g ^ r7) << 3)]);
      short8 vf1 = *(const short8*)(&Vs[buf][row * 64 + (((4 + g) ^ r7) << 3)]);
      acc[fh] = __builtin_amdgcn_mfma_f32_16x16x32_bf16(pf0, vf0, acc[fh], 0, 0, 0);
      acc[fh] = __builtin_amdgcn_mfma_f32_16x16x32_bf16(pf1, vf1, acc[fh], 0, 0, 0);
    }
    __builtin_amdgcn_s_setprio(0);

    __syncthreads();
    buf ^= 1;
  }

  float inv[4];
#pragma unroll
  for (int r = 0; r < 4; ++r) inv[r] = 1.0f / l[r];
#pragma unroll
  for (int fh = 0; fh < 8; ++fh)
#pragma unroll
    for (int r = 0; r < 4; ++r) {
      int tg = qt * 64 + w * 16 + g * 4 + r;
      attn[((size_t)b * T_SEQ + tg) * D_MODEL + (size_t)h * HEAD_DIM + fh * 16 + l15] =
          f2bf(acc[fh][r] * inv[r]);
    }
}

// ---------------- launch ----------------
extern "C" void kernel_launch(void* const* d_in, const int* in_sizes, int n_in,
                              void* d_out, int out_size, void* d_ws, size_t ws_size,
                              hipStream_t stream) {
  const float* x    = (const float*)d_in[0];
  const float* cosb = (const float*)d_in[1];
  const float* sinb = (const float*)d_in[2];
  const float* Wqkv = (const float*)d_in[3];
  const float* Wout = (const float*)d_in[4];
  float* out = (float*)d_out;

  char* ws = (char*)d_ws;
  size_t off = 0;
  bf16_t* xb    = (bf16_t*)(ws + off); off += (size_t)4096 * 2048 * 2;
  bf16_t* wqkvb = (bf16_t*)(ws + off); off += (size_t)6144 * 2048 * 2;
  bf16_t* woutb = (bf16_t*)(ws + off); off += (size_t)2048 * 2048 * 2;
  bf16_t* qkvb  = (bf16_t*)(ws + off); off += (size_t)4096 * 6144 * 2;
  bf16_t* qb    = (bf16_t*)(ws + off); off += (size_t)32 * 2048 * 128 * 2;
  bf16_t* kb    = (bf16_t*)(ws + off); off += (size_t)32 * 2048 * 128 * 2;
  bf16_t* vTb   = (bf16_t*)(ws + off); off += (size_t)32 * 2048 * 128 * 2;
  bf16_t* attnb = xb;  // xb dead after QKV GEMM

  cvt_kernel<<<8192, 256, 0, stream>>>(x, (unsigned short*)xb, 4096 * 2048 / 4);
  cvt_kernel<<<12288, 256, 0, stream>>>(Wqkv, (unsigned short*)wqkvb, 6144 * 2048 / 4);
  cvt_kernel<<<4096, 256, 0, stream>>>(Wout, (unsigned short*)woutb, 2048 * 2048 / 4);

  // QKV: M=4096, N=6144 -> 16x24 = 384 blocks (384 % 8 == 0)
  gemm8p_kernel<0><<<384, 512, 0, stream>>>(xb, wqkvb, nullptr, (unsigned short*)qkvb,
                                            4096, 6144, 2048, 24);

  rope_kernel<<<1024, 256, 0, stream>>>(qkvb, cosb, sinb, qb, kb, vTb);

  attn_kernel<<<1024, 256, 0, stream>>>(qb, kb, vTb, (unsigned short*)attnb);

  // out-proj: M=4096, N=2048 -> 16x8 = 128 blocks
  gemm8p_kernel<1><<<128, 512, 0, stream>>>(attnb, woutb, out, nullptr,
                                            4096, 2048, 2048, 8);
}